// Round 1
// baseline (139.999 us; speedup 1.0000x reference)
//
#include <hip/hip_runtime.h>
#include <hip/hip_bf16.h>

typedef float f32x4  __attribute__((ext_vector_type(4)));
typedef short bf16x8 __attribute__((ext_vector_type(8)));

#define BM 128
#define BN 128
#define BK 64

// round-to-nearest-even f32 -> bf16 bits (inputs are finite normals)
__device__ __forceinline__ short bf16r(float x) {
    unsigned u = __builtin_bit_cast(unsigned, x);
    u += 0x7fffu + ((u >> 16) & 1u);
    return (short)(u >> 16);
}

// out[b,l,i,o] = sum_j head[b,i,j] * U[l,j] * dep[b,o,j]
// One block = one (b,l,i-tile,o-tile): C[128,128] = (head_tile * U[l]) @ dep_tile^T
__global__ __launch_bounds__(256, 2)
void bla_gemm(const float* __restrict__ head,
              const float* __restrict__ dep,
              const float* __restrict__ U,
              float* __restrict__ out)
{
    constexpr int S = 512, D = 512, L = 32;
    constexpr int NT = D / BK;  // 8 K-steps

    // double-buffered swizzled bf16 tiles: 2*(16KB+16KB) = 64KB
    __shared__ short Al[2][BM * BK];
    __shared__ short Bl[2][BN * BK];

    const int tid  = threadIdx.x;
    const int lane = tid & 63;
    const int wid  = tid >> 6;
    const int wm   = wid >> 1;   // wave tile row (2x2 waves of 64x64)
    const int wn   = wid & 1;

    // XCD swizzle (grid=4096, 4096%8==0 -> simple bijective form OK).
    // XCD x gets a contiguous 512-block chunk == all work for batch b=x,
    // so head[b]+dep[b] (2MB f32) stays resident in that XCD's 4MB L2.
    const int swz = (blockIdx.x & 7) * ((int)gridDim.x >> 3) + (blockIdx.x >> 3);
    const int b   = swz >> 9;          // 0..7
    const int rem = swz & 511;
    const int l   = rem >> 4;          // 0..31
    const int it  = (rem >> 2) & 3;
    const int ot  = rem & 3;
    const int i0  = it * BM;
    const int o0  = ot * BN;

    // staging geometry: 256 threads; 8 threads/row * 8 f32 each; 4 passes of 32 rows
    const int srow = tid >> 3;         // 0..31
    const int scol = (tid & 7) * 8;    // 0..56 (element col)
    const int swb  = scol * 2;         // byte col in LDS row (128B rows)

    const float* hb = head + (size_t)(b * S + i0 + srow) * D + scol;
    const float* db = dep  + (size_t)(b * S + o0 + srow) * D + scol;
    const float* ub = U + l * D + scol;

    f32x4 ra[4][2], rb[4][2], ru[2];

    // issue global loads for K-step t (early: latency hides under MFMA phase)
#define STAGE_LOAD(t) do {                                                     \
        const int k0_ = (t) * BK;                                              \
        ru[0] = *(const f32x4*)(ub + k0_);                                     \
        ru[1] = *(const f32x4*)(ub + k0_ + 4);                                 \
        _Pragma("unroll")                                                      \
        for (int p_ = 0; p_ < 4; ++p_) {                                       \
            ra[p_][0] = *(const f32x4*)(hb + k0_ + p_ * 32 * D);               \
            ra[p_][1] = *(const f32x4*)(hb + k0_ + p_ * 32 * D + 4);           \
            rb[p_][0] = *(const f32x4*)(db + k0_ + p_ * 32 * D);               \
            rb[p_][1] = *(const f32x4*)(db + k0_ + p_ * 32 * D + 4);           \
        }                                                                      \
    } while (0)

    // scale A by U, convert to bf16, swizzled ds_write_b128 (late: after barrier)
#define STAGE_WRITE(buf) do {                                                  \
        _Pragma("unroll")                                                      \
        for (int p_ = 0; p_ < 4; ++p_) {                                       \
            const int row_ = srow + p_ * 32;                                   \
            const int sb_  = swb ^ ((row_ & 7) << 4);                          \
            bf16x8 av_, bv_;                                                   \
            _Pragma("unroll")                                                  \
            for (int q_ = 0; q_ < 2; ++q_) {                                   \
                _Pragma("unroll")                                              \
                for (int j_ = 0; j_ < 4; ++j_) {                               \
                    av_[q_ * 4 + j_] = bf16r(ra[p_][q_][j_] * ru[q_][j_]);     \
                    bv_[q_ * 4 + j_] = bf16r(rb[p_][q_][j_]);                  \
                }                                                              \
            }                                                                  \
            *(bf16x8*)&Al[buf][row_ * BK + (sb_ >> 1)] = av_;                  \
            *(bf16x8*)&Bl[buf][row_ * BK + (sb_ >> 1)] = bv_;                  \
        }                                                                      \
    } while (0)

    f32x4 acc[4][4];
#pragma unroll
    for (int i = 0; i < 4; ++i)
#pragma unroll
        for (int j = 0; j < 4; ++j)
            acc[i][j] = (f32x4){0.f, 0.f, 0.f, 0.f};

    const int cbase = (lane >> 4) << 4;       // byte offset of lane's k-slice
    const int rsw   = (lane & 7) << 4;        // read-side swizzle term

#define COMPUTE(buf) do {                                                      \
        _Pragma("unroll")                                                      \
        for (int ks_ = 0; ks_ < 2; ++ks_) {                                    \
            const int sb2_ = (ks_ * 64 + cbase) ^ rsw;                         \
            bf16x8 af_[4], bfr_[4];                                            \
            _Pragma("unroll")                                                  \
            for (int f_ = 0; f_ < 4; ++f_) {                                   \
                af_[f_]  = *(const bf16x8*)&Al[buf][(wm * 64 + f_ * 16 +       \
                              (lane & 15)) * BK + (sb2_ >> 1)];                \
                bfr_[f_] = *(const bf16x8*)&Bl[buf][(wn * 64 + f_ * 16 +       \
                              (lane & 15)) * BK + (sb2_ >> 1)];                \
            }                                                                  \
            _Pragma("unroll")                                                  \
            for (int fm_ = 0; fm_ < 4; ++fm_)                                  \
                _Pragma("unroll")                                              \
                for (int fn_ = 0; fn_ < 4; ++fn_)                              \
                    acc[fm_][fn_] = __builtin_amdgcn_mfma_f32_16x16x32_bf16(   \
                        af_[fm_], bfr_[fn_], acc[fm_][fn_], 0, 0, 0);          \
        }                                                                      \
    } while (0)

    // prologue
    STAGE_LOAD(0);
    STAGE_WRITE(0);
    __syncthreads();

    int cur = 0;
#pragma unroll
    for (int t = 0; t < NT; ++t) {
        if (t + 1 < NT) STAGE_LOAD(t + 1);   // global->reg, overlaps MFMA below
        COMPUTE(cur);
        if (t + 1 < NT) STAGE_WRITE(cur ^ 1); // reg->LDS into the other buffer
        __syncthreads();
        cur ^= 1;
    }

    // epilogue: C[i,o] f32; col = lane&15, row = (lane>>4)*4 + r (verified m89/m91)
    float* op = out + (size_t)(b * L + l) * S * S;
#pragma unroll
    for (int fm = 0; fm < 4; ++fm) {
        const int row0 = i0 + wm * 64 + fm * 16 + ((lane >> 4) << 2);
#pragma unroll
        for (int fn = 0; fn < 4; ++fn) {
            const int col = o0 + wn * 64 + fn * 16 + (lane & 15);
#pragma unroll
            for (int r = 0; r < 4; ++r)
                op[(size_t)(row0 + r) * S + col] = acc[fm][fn][r];
        }
    }

#undef STAGE_LOAD
#undef STAGE_WRITE
#undef COMPUTE
}

extern "C" void kernel_launch(void* const* d_in, const int* in_sizes, int n_in,
                              void* d_out, int out_size, void* d_ws, size_t ws_size,
                              hipStream_t stream)
{
    const float* head = (const float*)d_in[0];
    const float* dep  = (const float*)d_in[1];
    const float* U    = (const float*)d_in[2];
    float* out        = (float*)d_out;

    // grid: b(8) x l(32) x it(4) x ot(4) = 4096 blocks, 256 threads
    bla_gemm<<<dim3(8 * 32 * 4 * 4), dim3(256), 0, stream>>>(head, dep, U, out);
}

// Round 2
// 128.069 us; speedup vs baseline: 1.0932x; 1.0932x over previous
//
#include <hip/hip_runtime.h>
#include <hip/hip_bf16.h>

typedef float f32x4  __attribute__((ext_vector_type(4)));
typedef short bf16x8 __attribute__((ext_vector_type(8)));

// manual RNE f32->bf16 (prepass only; main path uses hardware cvt)
__device__ __forceinline__ short bf16r(float x) {
    unsigned u = __builtin_bit_cast(unsigned, x);
    u += 0x7fffu + ((u >> 16) & 1u);
    return (short)(u >> 16);
}

__device__ __forceinline__ short cvt_bf16(float x) {
    return __builtin_bit_cast(short, __float2bfloat16(x));
}

// prepass: dep f32 -> bf16 (2M elems, 8 per thread)
__global__ void cvt_dep_kernel(const float* __restrict__ in, short* __restrict__ out, int n8) {
    int i = blockIdx.x * blockDim.x + threadIdx.x;
    if (i < n8) {
        f32x4 a = *(const f32x4*)(in + (size_t)i * 8);
        f32x4 c = *(const f32x4*)(in + (size_t)i * 8 + 4);
        bf16x8 v;
#pragma unroll
        for (int j = 0; j < 4; ++j) { v[j] = bf16r(a[j]); v[4 + j] = bf16r(c[j]); }
        *(bf16x8*)(out + (size_t)i * 8) = v;
    }
}

// out[b,l,i,o] = sum_j head[b,i,j]*U[l,j]*dep[b,o,j]
// 256x256 tile per block, 8 waves (2Mx4N, wave tile 128x64), BK=64, dbuf LDS 128KB.
template<bool USE_WS>
__global__ __launch_bounds__(512, 2)
void bla_gemm2(const float* __restrict__ head,
               const float* __restrict__ dep,    // f32 fallback path
               const short* __restrict__ depb,   // bf16 (USE_WS)
               const float* __restrict__ U,
               float* __restrict__ out)
{
    constexpr int S = 512, D = 512, L = 32;
    constexpr int BM = 256, BN = 256, BK = 64, NT = D / BK;

    __shared__ short Al[2][BM * BK];   // 32KB each buf
    __shared__ short Bl[2][BN * BK];   // total 128KB

    const int tid  = threadIdx.x;
    const int lane = tid & 63;
    const int wid  = tid >> 6;   // 0..7
    const int wm   = wid >> 2;   // 0..1
    const int wn   = wid & 3;    // 0..3

    // XCD swizzle: 1024 blocks, 128/XCD == all tiles of one b -> L2 locality.
    const int swz = (blockIdx.x & 7) * ((int)gridDim.x >> 3) + (blockIdx.x >> 3);
    const int b   = swz >> 7;
    const int rem = swz & 127;
    // it-major within the XCD chunk: 64 consecutive blocks share one 4MB A-panel
    const int it  = rem >> 6;
    const int l   = (rem >> 1) & 31;
    const int ot  = rem & 1;
    const int i0  = it * BM;
    const int o0  = ot * BN;

    // ---- A staging geometry (reg path: f32 load, *U, cvt, swizzled ds_write)
    const int ar = tid >> 3;          // 0..63 (4 passes of 64 rows)
    const int ac = (tid & 7) * 8;     // elem col within BK
    const float* hb = head + (size_t)(b * S + i0 + ar) * D + ac;
    const float* ub = U + (size_t)l * D + ac;
    // swizzled byte col, row&7 == (tid>>3)&7 constant per thread
    const int aswb = ((tid & 7) * 16) ^ ((ar & 7) << 4);

    f32x4 ra[4][2], ru[2];
    f32x4 rbf[4][2];                  // fallback B regs
    const float* db = dep + (size_t)(b * S + o0 + ar) * D + ac;

    // ---- B staging via global_load_lds (linear dest, pre-swizzled source)
    const int bsrc_off = ((lane & 7) * 16) ^ ((lane >> 3) << 4); // byte off in 128B row window

#define STAGE_B_G(t, buf) do {                                                     \
        _Pragma("unroll")                                                          \
        for (int q_ = 0; q_ < 4; ++q_) {                                           \
            const int r_ = wid * 32 + q_ * 8 + (lane >> 3);                        \
            const char* src_ = (const char*)depb +                                 \
                ((size_t)(b * S + o0 + r_) * D + (size_t)(t) * BK) * 2 + bsrc_off; \
            short* dst_ = &Bl[buf][(wid * 32 + q_ * 8) * BK] + lane * 8;           \
            __builtin_amdgcn_global_load_lds(                                      \
                (const __attribute__((address_space(1))) void*)src_,               \
                (__attribute__((address_space(3))) void*)dst_, 16, 0, 0);          \
        }                                                                          \
    } while (0)

#define STAGE_A_LOAD(t) do {                                                       \
        const int k0_ = (t) * BK;                                                  \
        ru[0] = *(const f32x4*)(ub + k0_);                                         \
        ru[1] = *(const f32x4*)(ub + k0_ + 4);                                     \
        _Pragma("unroll")                                                          \
        for (int p_ = 0; p_ < 4; ++p_) {                                           \
            ra[p_][0] = *(const f32x4*)(hb + k0_ + (size_t)p_ * 64 * D);           \
            ra[p_][1] = *(const f32x4*)(hb + k0_ + (size_t)p_ * 64 * D + 4);       \
        }                                                                          \
    } while (0)

#define STAGE_A_WRITE(buf) do {                                                    \
        _Pragma("unroll")                                                          \
        for (int p_ = 0; p_ < 4; ++p_) {                                           \
            bf16x8 av_;                                                            \
            _Pragma("unroll")                                                      \
            for (int q_ = 0; q_ < 2; ++q_)                                         \
                _Pragma("unroll")                                                  \
                for (int j_ = 0; j_ < 4; ++j_)                                     \
                    av_[q_ * 4 + j_] = cvt_bf16(ra[p_][q_][j_] * ru[q_][j_]);      \
            *(bf16x8*)&Al[buf][(ar + p_ * 64) * BK + (aswb >> 1)] = av_;           \
        }                                                                          \
    } while (0)

#define STAGE_B_LOAD(t) do {                                                       \
        const int k0_ = (t) * BK;                                                  \
        _Pragma("unroll")                                                          \
        for (int p_ = 0; p_ < 4; ++p_) {                                           \
            rbf[p_][0] = *(const f32x4*)(db + k0_ + (size_t)p_ * 64 * D);          \
            rbf[p_][1] = *(const f32x4*)(db + k0_ + (size_t)p_ * 64 * D + 4);      \
        }                                                                          \
    } while (0)

#define STAGE_B_WRITE(buf) do {                                                    \
        _Pragma("unroll")                                                          \
        for (int p_ = 0; p_ < 4; ++p_) {                                           \
            bf16x8 bv_;                                                            \
            _Pragma("unroll")                                                      \
            for (int q_ = 0; q_ < 2; ++q_)                                         \
                _Pragma("unroll")                                                  \
                for (int j_ = 0; j_ < 4; ++j_)                                     \
                    bv_[q_ * 4 + j_] = cvt_bf16(rbf[p_][q_][j_]);                  \
            *(bf16x8*)&Bl[buf][(ar + p_ * 64) * BK + (aswb >> 1)] = bv_;           \
        }                                                                          \
    } while (0)

    f32x4 acc[8][4];
#pragma unroll
    for (int i = 0; i < 8; ++i)
#pragma unroll
        for (int j = 0; j < 4; ++j)
            acc[i][j] = (f32x4){0.f, 0.f, 0.f, 0.f};

#define COMPUTE_KS(buf, ks) do {                                                   \
        const int cb_ = ((ks) * 64 + ((lane >> 4) << 4));                          \
        bf16x8 af_[8], bfr_[4];                                                    \
        _Pragma("unroll")                                                          \
        for (int f_ = 0; f_ < 8; ++f_) {                                           \
            const int row_ = wm * 128 + f_ * 16 + (lane & 15);                     \
            af_[f_] = *(const bf16x8*)                                             \
                &Al[buf][row_ * BK + ((cb_ ^ ((row_ & 7) << 4)) >> 1)];            \
        }                                                                          \
        _Pragma("unroll")                                                          \
        for (int f_ = 0; f_ < 4; ++f_) {                                           \
            const int row_ = wn * 64 + f_ * 16 + (lane & 15);                      \
            bfr_[f_] = *(const bf16x8*)                                            \
                &Bl[buf][row_ * BK + ((cb_ ^ ((row_ & 7) << 4)) >> 1)];            \
        }                                                                          \
        _Pragma("unroll")                                                          \
        for (int m_ = 0; m_ < 8; ++m_)                                             \
            _Pragma("unroll")                                                      \
            for (int n_ = 0; n_ < 4; ++n_)                                         \
                acc[m_][n_] = __builtin_amdgcn_mfma_f32_16x16x32_bf16(             \
                    af_[m_], bfr_[n_], acc[m_][n_], 0, 0, 0);                      \
    } while (0)

    // prologue
    if constexpr (USE_WS) STAGE_B_G(0, 0); else STAGE_B_LOAD(0);
    STAGE_A_LOAD(0);
    STAGE_A_WRITE(0);
    if constexpr (!USE_WS) STAGE_B_WRITE(0);
    __syncthreads();

    int cur = 0;
#pragma unroll
    for (int t = 0; t < NT; ++t) {
        if (t + 1 < NT) {
            if constexpr (USE_WS) STAGE_B_G(t + 1, cur ^ 1); else STAGE_B_LOAD(t + 1);
            STAGE_A_LOAD(t + 1);       // VMEM issued early: hides under MFMA below
        }
        COMPUTE_KS(cur, 0);
        if (t + 1 < NT) {
            STAGE_A_WRITE(cur ^ 1);    // write-late (T14): compiler waits vmcnt here
            if constexpr (!USE_WS) STAGE_B_WRITE(cur ^ 1);
        }
        COMPUTE_KS(cur, 1);
        __syncthreads();
        cur ^= 1;
    }

    // epilogue: C/D layout col=lane&15, row=(lane>>4)*4+r (m89/m91)
    float* op = out + (size_t)(b * L + l) * S * S;
#pragma unroll
    for (int m_ = 0; m_ < 8; ++m_) {
        const int row0 = i0 + wm * 128 + m_ * 16 + ((lane >> 4) << 2);
#pragma unroll
        for (int n_ = 0; n_ < 4; ++n_) {
            const int col = o0 + wn * 64 + n_ * 16 + (lane & 15);
#pragma unroll
            for (int r_ = 0; r_ < 4; ++r_)
                op[(size_t)(row0 + r_) * S + col] = acc[m_][n_][r_];
        }
    }

#undef STAGE_B_G
#undef STAGE_A_LOAD
#undef STAGE_A_WRITE
#undef STAGE_B_LOAD
#undef STAGE_B_WRITE
#undef COMPUTE_KS
}

extern "C" void kernel_launch(void* const* d_in, const int* in_sizes, int n_in,
                              void* d_out, int out_size, void* d_ws, size_t ws_size,
                              hipStream_t stream)
{
    const float* head = (const float*)d_in[0];
    const float* dep  = (const float*)d_in[1];
    const float* U    = (const float*)d_in[2];
    float* out        = (float*)d_out;

    const size_t need = (size_t)8 * 512 * 512 * 2;   // dep in bf16: 4MB
    if (ws_size >= need) {
        short* depb = (short*)d_ws;
        cvt_dep_kernel<<<dim3(1024), dim3(256), 0, stream>>>(dep, depb, 262144);
        bla_gemm2<true><<<dim3(1024), dim3(512), 0, stream>>>(head, dep, depb, U, out);
    } else {
        bla_gemm2<false><<<dim3(1024), dim3(512), 0, stream>>>(head, nullptr ? nullptr : dep, nullptr, U, out);
    }
}

// Round 3
// 127.347 us; speedup vs baseline: 1.0993x; 1.0057x over previous
//
#include <hip/hip_runtime.h>
#include <hip/hip_bf16.h>

typedef float f32x4  __attribute__((ext_vector_type(4)));
typedef short bf16x8 __attribute__((ext_vector_type(8)));

__device__ __forceinline__ short bf16r(float x) {
    unsigned u = __builtin_bit_cast(unsigned, x);
    u += 0x7fffu + ((u >> 16) & 1u);
    return (short)(u >> 16);
}

// prepass: head (2M elems) + dep (2M elems) f32 -> bf16 into ws
__global__ void cvt_kernel(const float* __restrict__ head, const float* __restrict__ dep,
                           short* __restrict__ hb, short* __restrict__ db) {
    const int n8 = 8 * 512 * 512 / 8;  // 262144 chunks of 8 per tensor
    int i = blockIdx.x * blockDim.x + threadIdx.x;
    const float* src = (i < n8) ? head : dep;
    short* dst = (i < n8) ? hb : db;
    int j = (i < n8) ? i : i - n8;
    f32x4 a = *(const f32x4*)(src + (size_t)j * 8);
    f32x4 c = *(const f32x4*)(src + (size_t)j * 8 + 4);
    bf16x8 v;
#pragma unroll
    for (int e = 0; e < 4; ++e) { v[e] = bf16r(a[e]); v[4 + e] = bf16r(c[e]); }
    *(bf16x8*)(dst + (size_t)j * 8) = v;
}

// ---------------- main kernel: 256x256 tile, 8 waves, 4-phase/K-tile schedule ----
__global__ __launch_bounds__(512, 2)
void bla_gemm3(const short* __restrict__ headb,
               const short* __restrict__ depb,
               const float* __restrict__ U,
               float* __restrict__ out)
{
    constexpr int S = 512, D = 512, L = 32, BM = 256, BN = 256, BK = 64, NT = 8;

    __shared__ __align__(16) short Al[2][BM * BK];   // 32KB each
    __shared__ __align__(16) short Bl[2][BN * BK];   // total 128KB

    const int tid = threadIdx.x, lane = tid & 63, wid = tid >> 6;
    const int wm = wid >> 2, wn = wid & 3;           // 2M x 4N waves, wave tile 128x64

    // XCD swizzle: 1024 blocks, 128/XCD -> one b per XCD (bf16 panels 1MB, L2-resident)
    const int swz = (blockIdx.x & 7) * ((int)gridDim.x >> 3) + (blockIdx.x >> 3);
    const int b = swz >> 7, rem = swz & 127;
    const int it = rem >> 6, l = (rem >> 1) & 31, ot = rem & 1;
    const int i0 = it * BM, o0 = ot * BN;

    // A staging geometry: 512 thr, 8/row x 8 bf16, 4 passes of 64 rows
    const int ar = tid >> 3, ac = (tid & 7) * 8;
    const short* hbase = headb + (size_t)(b * S + i0 + ar) * D + ac;
    const float* ubase = U + (size_t)l * D + ac;
    const int awoff = ((((tid & 7) * 16) ^ ((ar & 7) << 4)) >> 1);  // swizzled short idx in row

    // B gload: linear LDS dest, inverse-swizzled global source (rule #21)
    const int bso = ((lane & 7) * 16) ^ ((lane >> 3) << 4);
    const short* dbase = depb + (size_t)(b * S + o0) * D;

    bf16x8 rA[4];
    float  ruf[8];

#define A_ISSUE(t_) do {                                                        \
        _Pragma("unroll")                                                       \
        for (int p = 0; p < 4; ++p)                                             \
            rA[p] = *(const bf16x8*)(hbase + (size_t)(p * 64) * D + (t_) * BK); \
        f32x4 u0 = *(const f32x4*)(ubase + (t_) * BK);                          \
        f32x4 u1 = *(const f32x4*)(ubase + (t_) * BK + 4);                      \
        _Pragma("unroll")                                                       \
        for (int e = 0; e < 4; ++e) { ruf[e] = u0[e]; ruf[4 + e] = u1[e]; }     \
    } while (0)

#define A_WRITE(buf_) do {                                                      \
        _Pragma("unroll")                                                       \
        for (int p = 0; p < 4; ++p) {                                           \
            bf16x8 av;                                                          \
            _Pragma("unroll")                                                   \
            for (int e = 0; e < 8; ++e) {                                       \
                float f = __builtin_bit_cast(float,                             \
                    (unsigned)((unsigned short)rA[p][e]) << 16) * ruf[e];       \
                av[e] = bf16r(f);                                               \
            }                                                                   \
            *(bf16x8*)&Al[buf_][(ar + p * 64) * BK + awoff] = av;               \
        }                                                                       \
    } while (0)

#define B_ISSUE(t_, buf_) do {                                                  \
        _Pragma("unroll")                                                       \
        for (int q = 0; q < 4; ++q) {                                           \
            const int rg = wid * 32 + q * 8 + (lane >> 3);                      \
            const char* s_ = (const char*)dbase +                               \
                ((size_t)rg * D + (size_t)(t_) * BK) * 2 + bso;                 \
            __builtin_amdgcn_global_load_lds(                                   \
                (const __attribute__((address_space(1))) void*)s_,              \
                (__attribute__((address_space(3))) void*)&Bl[buf_][(wid * 32 + q * 8) * BK], \
                16, 0, 0);                                                      \
        }                                                                       \
    } while (0)

    f32x4 acc[8][4] = {};
    bf16x8 bfr[4];

#define DSREAD_A(buf_, mh_, ks_, af_) do {                                      \
        const int cb = (ks_) * 64 + ((lane >> 4) << 4);                         \
        _Pragma("unroll")                                                       \
        for (int f = 0; f < 4; ++f) {                                           \
            const int row = wm * 128 + ((mh_) * 4 + f) * 16 + (lane & 15);      \
            af_[f] = *(const bf16x8*)&Al[buf_][row * BK + ((cb ^ ((row & 7) << 4)) >> 1)]; \
        }                                                                       \
    } while (0)

#define DSREAD_B(buf_, ks_) do {                                                \
        const int cb = (ks_) * 64 + ((lane >> 4) << 4);                         \
        _Pragma("unroll")                                                       \
        for (int f = 0; f < 4; ++f) {                                           \
            const int row = wn * 64 + f * 16 + (lane & 15);                     \
            bfr[f] = *(const bf16x8*)&Bl[buf_][row * BK + ((cb ^ ((row & 7) << 4)) >> 1)]; \
        }                                                                       \
    } while (0)

#define MFMA16(mh_, af_) do {                                                   \
        __builtin_amdgcn_s_setprio(1);                                          \
        _Pragma("unroll")                                                       \
        for (int m = 0; m < 4; ++m)                                             \
            _Pragma("unroll")                                                   \
            for (int n = 0; n < 4; ++n)                                         \
                acc[(mh_) * 4 + m][n] = __builtin_amdgcn_mfma_f32_16x16x32_bf16(\
                    af_[m], bfr[n], acc[(mh_) * 4 + m][n], 0, 0, 0);            \
        __builtin_amdgcn_s_setprio(0);                                          \
    } while (0)

#define SB()  __builtin_amdgcn_sched_barrier(0)
#define BAR() __builtin_amdgcn_s_barrier()

    // prologue: stage tile 0 (A regs first, then B gloads; drain everything once)
    A_ISSUE(0);
    B_ISSUE(0, 0);
    A_WRITE(0);
    asm volatile("s_waitcnt vmcnt(0) lgkmcnt(0)");
    BAR();

#pragma unroll
    for (int t = 0; t < NT; ++t) {
        const int c = t & 1;
        bf16x8 af[4];
        // ---- ph0: issue next-tile staging (A regs then B gloads), read mh0/ks0
        if (t < NT - 1) { A_ISSUE(t + 1); B_ISSUE(t + 1, c ^ 1); }
        DSREAD_A(c, 0, 0, af); DSREAD_B(c, 0);
        SB(); BAR();
        MFMA16(0, af);
        SB(); BAR();
        // ---- ph1: read mh1/ks0 (reuse bfr)
        DSREAD_A(c, 1, 0, af);
        SB(); BAR();
        MFMA16(1, af);
        SB(); BAR();
        // ---- ph2: scale+convert+write next A (compiler vmcnt leaves B in flight)
        if (t < NT - 1) A_WRITE(c ^ 1);
        DSREAD_A(c, 0, 1, af); DSREAD_B(c, 1);
        SB(); BAR();
        MFMA16(0, af);
        SB(); BAR();
        // ---- ph3: read mh1/ks1; end-of-tile drain (loads issued 3 phases ago, L2-hit)
        DSREAD_A(c, 1, 1, af);
        SB(); BAR();
        MFMA16(1, af);
        SB();
        asm volatile("s_waitcnt vmcnt(0) lgkmcnt(0)");
        BAR();
    }

    // epilogue: C/D layout col=lane&15, row=(lane>>4)*4+r
    float* op = out + (size_t)(b * L + l) * S * S;
#pragma unroll
    for (int m = 0; m < 8; ++m) {
        const int row0 = i0 + wm * 128 + m * 16 + ((lane >> 4) << 2);
#pragma unroll
        for (int n = 0; n < 4; ++n) {
            const int col = o0 + wn * 64 + n * 16 + (lane & 15);
#pragma unroll
            for (int r = 0; r < 4; ++r)
                op[(size_t)(row0 + r) * S + col] = acc[m][n][r];
        }
    }

#undef A_ISSUE
#undef A_WRITE
#undef B_ISSUE
#undef DSREAD_A
#undef DSREAD_B
#undef MFMA16
#undef SB
#undef BAR
}

// ---------------- fallback (proven R1 kernel): used only if ws < 8MB ----------
__global__ __launch_bounds__(256, 2)
void bla_fb(const float* __restrict__ head, const float* __restrict__ dep,
            const float* __restrict__ U, float* __restrict__ out)
{
    constexpr int S = 512, D = 512, L = 32, BM = 128, BN = 128, BK = 64, NT = 8;
    __shared__ short Al[2][BM * BK];
    __shared__ short Bl[2][BN * BK];
    const int tid = threadIdx.x, lane = tid & 63, wid = tid >> 6;
    const int wm = wid >> 1, wn = wid & 1;
    const int swz = (blockIdx.x & 7) * ((int)gridDim.x >> 3) + (blockIdx.x >> 3);
    const int b = swz >> 9, rem = swz & 511;
    const int l = rem >> 4, it = (rem >> 2) & 3, ot = rem & 3;
    const int i0 = it * BM, o0 = ot * BN;
    const int srow = tid >> 3, scol = (tid & 7) * 8, swb = scol * 2;
    const float* hb = head + (size_t)(b * S + i0 + srow) * D + scol;
    const float* db = dep + (size_t)(b * S + o0 + srow) * D + scol;
    const float* ub = U + l * D + scol;
    f32x4 ra[4][2], rb[4][2], ru[2];
#define FSTAGE_LOAD(t) do { const int k0_ = (t) * BK;                              \
        ru[0] = *(const f32x4*)(ub + k0_); ru[1] = *(const f32x4*)(ub + k0_ + 4);  \
        _Pragma("unroll") for (int p_ = 0; p_ < 4; ++p_) {                         \
            ra[p_][0] = *(const f32x4*)(hb + k0_ + p_ * 32 * D);                   \
            ra[p_][1] = *(const f32x4*)(hb + k0_ + p_ * 32 * D + 4);               \
            rb[p_][0] = *(const f32x4*)(db + k0_ + p_ * 32 * D);                   \
            rb[p_][1] = *(const f32x4*)(db + k0_ + p_ * 32 * D + 4); } } while (0)
#define FSTAGE_WRITE(buf) do { _Pragma("unroll") for (int p_ = 0; p_ < 4; ++p_) {  \
            const int row_ = srow + p_ * 32; const int sb_ = swb ^ ((row_ & 7) << 4); \
            bf16x8 av_, bv_;                                                       \
            _Pragma("unroll") for (int q_ = 0; q_ < 2; ++q_)                       \
                _Pragma("unroll") for (int j_ = 0; j_ < 4; ++j_) {                 \
                    av_[q_ * 4 + j_] = bf16r(ra[p_][q_][j_] * ru[q_][j_]);         \
                    bv_[q_ * 4 + j_] = bf16r(rb[p_][q_][j_]); }                    \
            *(bf16x8*)&Al[buf][row_ * BK + (sb_ >> 1)] = av_;                      \
            *(bf16x8*)&Bl[buf][row_ * BK + (sb_ >> 1)] = bv_; } } while (0)
    f32x4 acc[4][4] = {};
    const int cbase = (lane >> 4) << 4, rsw = (lane & 7) << 4;
#define FCOMPUTE(buf) do { _Pragma("unroll") for (int ks_ = 0; ks_ < 2; ++ks_) {   \
            const int sb2_ = (ks_ * 64 + cbase) ^ rsw; bf16x8 af_[4], bfr_[4];     \
            _Pragma("unroll") for (int f_ = 0; f_ < 4; ++f_) {                     \
                af_[f_] = *(const bf16x8*)&Al[buf][(wm * 64 + f_ * 16 + (lane & 15)) * BK + (sb2_ >> 1)]; \
                bfr_[f_] = *(const bf16x8*)&Bl[buf][(wn * 64 + f_ * 16 + (lane & 15)) * BK + (sb2_ >> 1)]; } \
            _Pragma("unroll") for (int fm_ = 0; fm_ < 4; ++fm_)                    \
                _Pragma("unroll") for (int fn_ = 0; fn_ < 4; ++fn_)                \
                    acc[fm_][fn_] = __builtin_amdgcn_mfma_f32_16x16x32_bf16(       \
                        af_[fm_], bfr_[fn_], acc[fm_][fn_], 0, 0, 0); } } while (0)
    FSTAGE_LOAD(0); FSTAGE_WRITE(0); __syncthreads();
    int cur = 0;
#pragma unroll
    for (int t = 0; t < NT; ++t) {
        if (t + 1 < NT) FSTAGE_LOAD(t + 1);
        FCOMPUTE(cur);
        if (t + 1 < NT) FSTAGE_WRITE(cur ^ 1);
        __syncthreads();
        cur ^= 1;
    }
    float* op = out + (size_t)(b * L + l) * S * S;
#pragma unroll
    for (int fm = 0; fm < 4; ++fm) {
        const int row0 = i0 + wm * 64 + fm * 16 + ((lane >> 4) << 2);
#pragma unroll
        for (int fn = 0; fn < 4; ++fn) {
            const int col = o0 + wn * 64 + fn * 16 + (lane & 15);
#pragma unroll
            for (int r = 0; r < 4; ++r)
                op[(size_t)(row0 + r) * S + col] = acc[fm][fn][r];
        }
    }
#undef FSTAGE_LOAD
#undef FSTAGE_WRITE
#undef FCOMPUTE
}

extern "C" void kernel_launch(void* const* d_in, const int* in_sizes, int n_in,
                              void* d_out, int out_size, void* d_ws, size_t ws_size,
                              hipStream_t stream)
{
    const float* head = (const float*)d_in[0];
    const float* dep  = (const float*)d_in[1];
    const float* U    = (const float*)d_in[2];
    float* out        = (float*)d_out;

    const size_t nelem = (size_t)8 * 512 * 512;          // 2M per tensor
    const size_t need  = nelem * 2 * 2;                  // head+dep bf16: 8MB
    if (ws_size >= need) {
        short* headb = (short*)d_ws;
        short* depb  = headb + nelem;
        cvt_kernel<<<dim3(2048), dim3(256), 0, stream>>>(head, dep, headb, depb);
        bla_gemm3<<<dim3(1024), dim3(512), 0, stream>>>(headb, depb, U, out);
    } else {
        bla_fb<<<dim3(4096), dim3(256), 0, stream>>>(head, dep, U, out);
    }
}

// Round 4
// 111.430 us; speedup vs baseline: 1.2564x; 1.1428x over previous
//
#include <hip/hip_runtime.h>
#include <hip/hip_bf16.h>

typedef float f32x4  __attribute__((ext_vector_type(4)));
typedef short bf16x8 __attribute__((ext_vector_type(8)));

__device__ __forceinline__ short bf16r(float x) {
    unsigned u = __builtin_bit_cast(unsigned, x);
    u += 0x7fffu + ((u >> 16) & 1u);
    return (short)(u >> 16);
}

// prepass: head (2M) + dep (2M) f32 -> bf16 into ws
__global__ void cvt_kernel(const float* __restrict__ head, const float* __restrict__ dep,
                           short* __restrict__ hb, short* __restrict__ db) {
    const int n8 = 8 * 512 * 512 / 8;
    int i = blockIdx.x * blockDim.x + threadIdx.x;
    const float* src = (i < n8) ? head : dep;
    short* dst = (i < n8) ? hb : db;
    int j = (i < n8) ? i : i - n8;
    f32x4 a = *(const f32x4*)(src + (size_t)j * 8);
    f32x4 c = *(const f32x4*)(src + (size_t)j * 8 + 4);
    bf16x8 v;
#pragma unroll
    for (int e = 0; e < 4; ++e) { v[e] = bf16r(a[e]); v[4 + e] = bf16r(c[e]); }
    *(bf16x8*)(dst + (size_t)j * 8) = v;
}

// ---- main: 256x256 tile, 8 waves (2Mx4N), BK=64, counted-vmcnt 4-phase schedule
__global__ __launch_bounds__(512, 2)
void bla_gemm4(const short* __restrict__ headb,
               const short* __restrict__ depb,
               const float* __restrict__ U,
               float* __restrict__ out)
{
    constexpr int S = 512, D = 512, L = 32, BM = 256, BN = 256, BK = 64, NT = 8;

    __shared__ __align__(16) short Al[2][BM * BK];
    __shared__ __align__(16) short Bl[2][BN * BK];

    const int tid = threadIdx.x, lane = tid & 63, wid = tid >> 6;
    const int wm = wid >> 2, wn = wid & 3;   // wave tile 128x64

    const int swz = (blockIdx.x & 7) * ((int)gridDim.x >> 3) + (blockIdx.x >> 3);
    const int b = swz >> 7, rem = swz & 127;
    const int it = rem >> 6, l = (rem >> 1) & 31, ot = rem & 1;
    const int i0 = it * BM, o0 = ot * BN;

    // A staging: 512 thr, 8/row x 8 bf16, 4 stripes of 64 rows
    const int ar = tid >> 3, ac = (tid & 7) * 8;
    const short* hbase = headb + (size_t)(b * S + i0 + ar) * D + ac;
    const float* ubase = U + (size_t)l * D + ac;
    const int awoff = ((((tid & 7) * 16) ^ ((ar & 7) << 4)) >> 1);

    // B gload: linear LDS dest, inverse-swizzled source (rule #21)
    const int bso = ((lane & 7) * 16) ^ ((lane >> 3) << 4);
    const short* dbase = depb + (size_t)(b * S + o0) * D;

    bf16x8 rA[2][4];        // double-buffered A staging regs (static idx after unroll)
    f32x4  ru[2][2];

#define SBAR() __builtin_amdgcn_sched_barrier(0)

#define A_ISSUE(tt) do {                                                        \
        const int s_ = (tt) & 1;                                                \
        _Pragma("unroll")                                                       \
        for (int p = 0; p < 4; ++p)                                             \
            rA[s_][p] = *(const bf16x8*)(hbase + (size_t)(p * 64) * D + (tt) * BK); \
        ru[s_][0] = *(const f32x4*)(ubase + (tt) * BK);                         \
        ru[s_][1] = *(const f32x4*)(ubase + (tt) * BK + 4);                     \
    } while (0)

    // write stripes h*2, h*2+1 of tile tt into Al[(tt)&1] (scale by U, cvt bf16)
#define A_WRITE_H(tt, h) do {                                                   \
        const int s_ = (tt) & 1;                                                \
        _Pragma("unroll")                                                       \
        for (int p = (h) * 2; p < (h) * 2 + 2; ++p) {                           \
            bf16x8 av;                                                          \
            _Pragma("unroll")                                                   \
            for (int e = 0; e < 8; ++e) {                                       \
                float f = __builtin_bit_cast(float,                             \
                    (unsigned)((unsigned short)rA[s_][p][e]) << 16)             \
                    * ru[s_][e >> 2][e & 3];                                    \
                av[e] = __builtin_bit_cast(short, __float2bfloat16(f));         \
            }                                                                   \
            *(bf16x8*)&Al[s_][(ar + p * 64) * BK + awoff] = av;                 \
        }                                                                       \
    } while (0)

    // issue 2 of the 4 B gloads for tile tt into Bl[(tt)&1]
#define B_ISSUE_H(tt, h) do {                                                   \
        _Pragma("unroll")                                                       \
        for (int q = (h) * 2; q < (h) * 2 + 2; ++q) {                           \
            const int rg = wid * 32 + q * 8 + (lane >> 3);                      \
            const char* s_ = (const char*)dbase +                               \
                ((size_t)rg * D + (size_t)(tt) * BK) * 2 + bso;                 \
            __builtin_amdgcn_global_load_lds(                                   \
                (const __attribute__((address_space(1))) void*)s_,              \
                (__attribute__((address_space(3))) void*)&Bl[(tt) & 1][(wid * 32 + q * 8) * BK], \
                16, 0, 0);                                                      \
        }                                                                       \
    } while (0)

    f32x4 acc[8][4] = {};
    bf16x8 bfr[4];

#define DSREAD_A(buf_, mh_, ks_, af_) do {                                      \
        const int cb = (ks_) * 64 + ((lane >> 4) << 4);                         \
        _Pragma("unroll")                                                       \
        for (int f = 0; f < 4; ++f) {                                           \
            const int row = wm * 128 + ((mh_) * 4 + f) * 16 + (lane & 15);      \
            af_[f] = *(const bf16x8*)&Al[buf_][row * BK + ((cb ^ ((row & 7) << 4)) >> 1)]; \
        }                                                                       \
    } while (0)

#define DSREAD_B(buf_, ks_) do {                                                \
        const int cb = (ks_) * 64 + ((lane >> 4) << 4);                         \
        _Pragma("unroll")                                                       \
        for (int f = 0; f < 4; ++f) {                                           \
            const int row = wn * 64 + f * 16 + (lane & 15);                     \
            bfr[f] = *(const bf16x8*)&Bl[buf_][row * BK + ((cb ^ ((row & 7) << 4)) >> 1)]; \
        }                                                                       \
    } while (0)

#define MFMA16(mh_, af_) do {                                                   \
        __builtin_amdgcn_s_setprio(1);                                          \
        _Pragma("unroll")                                                       \
        for (int m = 0; m < 4; ++m)                                             \
            _Pragma("unroll")                                                   \
            for (int n = 0; n < 4; ++n)                                         \
                acc[(mh_) * 4 + m][n] = __builtin_amdgcn_mfma_f32_16x16x32_bf16(\
                    af_[m], bfr[n], acc[(mh_) * 4 + m][n], 0, 0, 0);            \
        __builtin_amdgcn_s_setprio(0);                                          \
    } while (0)

#define BAR() __builtin_amdgcn_s_barrier()

    // ---- prologue: stage tile0; prefetch A(1); counted drain of B(0) only
    A_ISSUE(0);
    B_ISSUE_H(0, 0); B_ISSUE_H(0, 1);
    SBAR();
    A_WRITE_H(0, 0); A_WRITE_H(0, 1);   // compiler auto vmcnt for rA[0]
    A_ISSUE(1);
    SBAR();
    asm volatile("s_waitcnt vmcnt(6) lgkmcnt(0)" ::: "memory");  // B(0) done; A(1)+U(1) in flight
    SBAR();
    BAR();
    SBAR();

#pragma unroll
    for (int t = 0; t < NT; ++t) {
        const int c = t & 1;
        bf16x8 af[4];

        // ---------- ph0: quadrant (mh0, ks0); issue B(t+1) first half
        DSREAD_A(c, 0, 0, af); DSREAD_B(c, 0);
        if (t + 1 < NT) B_ISSUE_H(t + 1, 0);
        SBAR(); BAR(); SBAR();
        MFMA16(0, af);
        SBAR(); BAR(); SBAR();

        // ---------- ph1: (mh1, ks0); issue B(t+1) second half
        DSREAD_A(c, 1, 0, af);
        if (t + 1 < NT) B_ISSUE_H(t + 1, 1);
        SBAR(); BAR(); SBAR();
        MFMA16(1, af);
        SBAR(); BAR(); SBAR();

        // ---------- ph2: (mh0, ks1); A-write stripes 0-1 (auto vmcnt(4): B in flight)
        DSREAD_A(c, 0, 1, af); DSREAD_B(c, 1);
        if (t + 1 < NT) A_WRITE_H(t + 1, 0);
        SBAR(); BAR(); SBAR();
        MFMA16(0, af);
        SBAR(); BAR(); SBAR();

        // ---------- ph3: (mh1, ks1); A-write stripes 2-3; prefetch A(t+2); counted tile-end wait
        DSREAD_A(c, 1, 1, af);
        if (t + 1 < NT) A_WRITE_H(t + 1, 1);
        if (t + 2 < NT) A_ISSUE(t + 2);
        SBAR(); BAR(); SBAR();
        MFMA16(1, af);
        SBAR();
        if (t + 2 < NT) {
            // outstanding: B(t+1)=4 oldest, A(t+2)+U(t+2)=6 newer -> wait B only
            asm volatile("s_waitcnt vmcnt(6) lgkmcnt(0)" ::: "memory");
        } else if (t + 1 < NT) {
            asm volatile("s_waitcnt vmcnt(0) lgkmcnt(0)" ::: "memory");
        }
        SBAR(); BAR(); SBAR();
    }

    // ---- epilogue: C/D layout col=lane&15, row=(lane>>4)*4+r
    float* op = out + (size_t)(b * L + l) * S * S;
#pragma unroll
    for (int m = 0; m < 8; ++m) {
        const int row0 = i0 + wm * 128 + m * 16 + ((lane >> 4) << 2);
#pragma unroll
        for (int n = 0; n < 4; ++n) {
            const int col = o0 + wn * 64 + n * 16 + (lane & 15);
#pragma unroll
            for (int r = 0; r < 4; ++r)
                op[(size_t)(row0 + r) * S + col] = acc[m][n][r];
        }
    }

#undef SBAR
#undef A_ISSUE
#undef A_WRITE_H
#undef B_ISSUE_H
#undef DSREAD_A
#undef DSREAD_B
#undef MFMA16
#undef BAR
}

// ---------------- fallback (proven R1 kernel): used only if ws < 8MB ----------
__global__ __launch_bounds__(256, 2)
void bla_fb(const float* __restrict__ head, const float* __restrict__ dep,
            const float* __restrict__ U, float* __restrict__ out)
{
    constexpr int S = 512, D = 512, L = 32, BM = 128, BN = 128, BK = 64, NT = 8;
    __shared__ short Al[2][BM * BK];
    __shared__ short Bl[2][BN * BK];
    const int tid = threadIdx.x, lane = tid & 63, wid = tid >> 6;
    const int wm = wid >> 1, wn = wid & 1;
    const int swz = (blockIdx.x & 7) * ((int)gridDim.x >> 3) + (blockIdx.x >> 3);
    const int b = swz >> 9, rem = swz & 511;
    const int l = rem >> 4, it = (rem >> 2) & 3, ot = rem & 3;
    const int i0 = it * BM, o0 = ot * BN;
    const int srow = tid >> 3, scol = (tid & 7) * 8, swb = scol * 2;
    const float* hb = head + (size_t)(b * S + i0 + srow) * D + scol;
    const float* db = dep + (size_t)(b * S + o0 + srow) * D + scol;
    const float* ub = U + l * D + scol;
    f32x4 ra[4][2], rb[4][2], ru[2];
#define FSTAGE_LOAD(t) do { const int k0_ = (t) * BK;                              \
        ru[0] = *(const f32x4*)(ub + k0_); ru[1] = *(const f32x4*)(ub + k0_ + 4);  \
        _Pragma("unroll") for (int p_ = 0; p_ < 4; ++p_) {                         \
            ra[p_][0] = *(const f32x4*)(hb + k0_ + p_ * 32 * D);                   \
            ra[p_][1] = *(const f32x4*)(hb + k0_ + p_ * 32 * D + 4);               \
            rb[p_][0] = *(const f32x4*)(db + k0_ + p_ * 32 * D);                   \
            rb[p_][1] = *(const f32x4*)(db + k0_ + p_ * 32 * D + 4); } } while (0)
#define FSTAGE_WRITE(buf) do { _Pragma("unroll") for (int p_ = 0; p_ < 4; ++p_) {  \
            const int row_ = srow + p_ * 32; const int sb_ = swb ^ ((row_ & 7) << 4); \
            bf16x8 av_, bv_;                                                       \
            _Pragma("unroll") for (int q_ = 0; q_ < 2; ++q_)                       \
                _Pragma("unroll") for (int j_ = 0; j_ < 4; ++j_) {                 \
                    av_[q_ * 4 + j_] = bf16r(ra[p_][q_][j_] * ru[q_][j_]);         \
                    bv_[q_ * 4 + j_] = bf16r(rb[p_][q_][j_]); }                    \
            *(bf16x8*)&Al[buf][row_ * BK + (sb_ >> 1)] = av_;                      \
            *(bf16x8*)&Bl[buf][row_ * BK + (sb_ >> 1)] = bv_; } } while (0)
    f32x4 acc[4][4] = {};
    const int cbase = (lane >> 4) << 4, rsw = (lane & 7) << 4;
#define FCOMPUTE(buf) do { _Pragma("unroll") for (int ks_ = 0; ks_ < 2; ++ks_) {   \
            const int sb2_ = (ks_ * 64 + cbase) ^ rsw; bf16x8 af_[4], bfr_[4];     \
            _Pragma("unroll") for (int f_ = 0; f_ < 4; ++f_) {                     \
                af_[f_] = *(const bf16x8*)&Al[buf][(wm * 64 + f_ * 16 + (lane & 15)) * BK + (sb2_ >> 1)]; \
                bfr_[f_] = *(const bf16x8*)&Bl[buf][(wn * 64 + f_ * 16 + (lane & 15)) * BK + (sb2_ >> 1)]; } \
            _Pragma("unroll") for (int fm_ = 0; fm_ < 4; ++fm_)                    \
                _Pragma("unroll") for (int fn_ = 0; fn_ < 4; ++fn_)                \
                    acc[fm_][fn_] = __builtin_amdgcn_mfma_f32_16x16x32_bf16(       \
                        af_[fm_], bfr_[fn_], acc[fm_][fn_], 0, 0, 0); } } while (0)
    FSTAGE_LOAD(0); FSTAGE_WRITE(0); __syncthreads();
    int cur = 0;
#pragma unroll
    for (int t = 0; t < NT; ++t) {
        if (t + 1 < NT) FSTAGE_LOAD(t + 1);
        FCOMPUTE(cur);
        if (t + 1 < NT) FSTAGE_WRITE(cur ^ 1);
        __syncthreads();
        cur ^= 1;
    }
    float* op = out + (size_t)(b * L + l) * S * S;
#pragma unroll
    for (int fm = 0; fm < 4; ++fm) {
        const int row0 = i0 + wm * 64 + fm * 16 + ((lane >> 4) << 2);
#pragma unroll
        for (int fn = 0; fn < 4; ++fn) {
            const int col = o0 + wn * 64 + fn * 16 + (lane & 15);
#pragma unroll
            for (int r = 0; r < 4; ++r)
                op[(size_t)(row0 + r) * S + col] = acc[fm][fn][r];
        }
    }
#undef FSTAGE_LOAD
#undef FSTAGE_WRITE
#undef FCOMPUTE
}

extern "C" void kernel_launch(void* const* d_in, const int* in_sizes, int n_in,
                              void* d_out, int out_size, void* d_ws, size_t ws_size,
                              hipStream_t stream)
{
    const float* head = (const float*)d_in[0];
    const float* dep  = (const float*)d_in[1];
    const float* U    = (const float*)d_in[2];
    float* out        = (float*)d_out;

    const size_t nelem = (size_t)8 * 512 * 512;
    const size_t need  = nelem * 2 * 2;   // 8MB
    if (ws_size >= need) {
        short* headb = (short*)d_ws;
        short* depb  = headb + nelem;
        cvt_kernel<<<dim3(2048), dim3(256), 0, stream>>>(head, dep, headb, depb);
        bla_gemm4<<<dim3(1024), dim3(512), 0, stream>>>(headb, depb, U, out);
    } else {
        bla_fb<<<dim3(4096), dim3(256), 0, stream>>>(head, dep, U, out);
    }
}